// Round 8
// baseline (294.587 us; speedup 1.0000x reference)
//
#include <hip/hip_runtime.h>
#include <hip/hip_fp16.h>
#include <math.h>
#include <stdint.h>

#define HH 512
#define WW 512
#define NIMG 24
#define CCH 3
#define TAU 0.25f
#define TVEPS 2e-4f
#define NUMEL 262144.0f
#define PTELEMS (NIMG * HH * WW)
#define NBLK 32   // blocks per image (8 x 4)

// ws layout:
// byte 0      : pd partials, 10 x 24 x 32 floats
// byte 32768  : pn partials, 10 x 24 x 32 floats
// byte 65536  : imgh (__half, 24*512*512 = 12.58 MB)
// byte 12648448: ptbuf[0..8], 9 snapshots x 25,165,824 B (ends ~239 MB)

__device__ __forceinline__ float2 h2f(uint32_t v) {
    __half2 h; *reinterpret_cast<uint32_t*>(&h) = v;
    return __half22float2(h);
}
__device__ __forceinline__ uint32_t f2h2(float a, float b) {
    __half2 h = __floats2half2_rn(a, b);
    return *reinterpret_cast<uint32_t*>(&h);
}

__device__ __forceinline__ void block_reduce_store(float v0, float v1,
                                                   float* p0, float* p1, int tid) {
    for (int off = 32; off > 0; off >>= 1) {
        v0 += __shfl_down(v0, off, 64);
        v1 += __shfl_down(v1, off, 64);
    }
    __shared__ float sr[2][4];
    int wave = tid >> 6, lane = tid & 63;
    if (lane == 0) { sr[0][wave] = v0; sr[1][wave] = v1; }
    __syncthreads();
    if (tid == 0) {
        *p0 = (sr[0][0] + sr[0][1]) + (sr[0][2] + sr[0][3]);
        *p1 = (sr[1][0] + sr[1][1]) + (sr[1][2] + sr[1][3]);
    }
}

// Iteration 0: out = img. Writes ptbuf[0], imgh, pn partials k=0.
// Tile 64 x 128, each thread an 8-row x 4-col strip.
__global__ __launch_bounds__(256, 3) void tv_step0(
    const float* __restrict__ img, const float* __restrict__ weight,
    __half* __restrict__ imgh, uint32_t* __restrict__ ptout,
    float* __restrict__ pd, float* __restrict__ pn)
{
    const int im = blockIdx.z;
    const int bid = blockIdx.y * 8 + blockIdx.x;
    const float w = weight[im / CCH];
    const float tw = TAU / w;
    const int x0 = blockIdx.x * 64, y0 = blockIdx.y * 128;
    const size_t ibase = (size_t)im * HH * WW;
    const float* imgI = img + ibase;
    __half* hI = imgh + ibase;
    uint32_t* pI = ptout + ibase;
    const int tid = threadIdx.x;
    const int tx = tid & 15, ty = tid >> 4;
    const int gx = x0 + 4 * tx;
    const int gy0 = y0 + 8 * ty;

    __shared__ float s2[16][68];

    float o[8][4];
    #pragma unroll
    for (int i = 0; i < 8; ++i) {
        float4 v = *(const float4*)(imgI + (size_t)(gy0 + i) * WW + gx);
        o[i][0] = v.x; o[i][1] = v.y; o[i][2] = v.z; o[i][3] = v.w;
    }
    float rh[8];
    if (tx == 15 && x0 + 64 < WW) {
        #pragma unroll
        for (int i = 0; i < 8; ++i)
            rh[i] = imgI[(size_t)(gy0 + i) * WW + x0 + 64];
    }
    float dh[4];
    if (ty == 15 && y0 + 128 < HH) {
        float4 v = *(const float4*)(imgI + (size_t)(y0 + 128) * WW + gx);
        dh[0] = v.x; dh[1] = v.y; dh[2] = v.z; dh[3] = v.w;
    }
    *(float4*)&s2[ty][4 * tx] = make_float4(o[0][0], o[0][1], o[0][2], o[0][3]);
    __syncthreads();

    float accn = 0.f;
    #pragma unroll
    for (int i = 0; i < 8; ++i) {
        const int gy = gy0 + i;
        float rt = __shfl_down(o[i][0], 1, 64);
        if (tx == 15) rt = (x0 + 64 < WW) ? rh[i] : 0.f;
        float dnv[4];
        if (i < 7) {
            dnv[0] = o[i + 1][0]; dnv[1] = o[i + 1][1];
            dnv[2] = o[i + 1][2]; dnv[3] = o[i + 1][3];
        } else if (ty < 15) {
            float4 t = *(float4*)&s2[ty + 1][4 * tx];
            dnv[0] = t.x; dnv[1] = t.y; dnv[2] = t.z; dnv[3] = t.w;
        } else {
            dnv[0] = dh[0]; dnv[1] = dh[1]; dnv[2] = dh[2]; dnv[3] = dh[3];
        }
        uint32_t pv[4];
        #pragma unroll
        for (int j = 0; j < 4; ++j) {
            float ov = o[i][j];
            float g0 = (gy < HH - 1) ? dnv[j] - ov : 0.f;
            float rn = (j < 3) ? o[i][j + 1] : rt;
            float g1 = (gx + j < WW - 1) ? rn - ov : 0.f;
            float ss2 = g0 * g0 + g1 * g1;
            float nrm = (ss2 > 0.f) ? sqrtf(ss2) : 0.f;
            accn += nrm;
            float inv = 1.f / (1.f + tw * nrm);
            pv[j] = f2h2(-TAU * g0 * inv, -TAU * g1 * inv);
        }
        size_t off = (size_t)gy * WW + gx;
        *(uint4*)(pI + off) = make_uint4(pv[0], pv[1], pv[2], pv[3]);
        *(uint2*)(hI + off) = make_uint2(f2h2(o[i][0], o[i][1]), f2h2(o[i][2], o[i][3]));
    }
    block_reduce_store(0.f, accn, &pd[im * NBLK + bid], &pn[im * NBLK + bid], tid);
}

// Iterations 1..8: unconditional TV step, snapshot write, partials k=it.
__global__ __launch_bounds__(256, 3) void tv_stepN(
    const __half* __restrict__ imgh, const float* __restrict__ weight,
    const uint32_t* __restrict__ pt_in, uint32_t* __restrict__ pt_out,
    float* __restrict__ pd, float* __restrict__ pn, int it)
{
    const int im = blockIdx.z;
    const int bid = blockIdx.y * 8 + blockIdx.x;
    const float w = weight[im / CCH];
    const float tw = TAU / w;
    const int x0 = blockIdx.x * 64, y0 = blockIdx.y * 128;
    const size_t ibase = (size_t)im * HH * WW;
    const __half* hI = imgh + ibase;
    const uint32_t* pinI = pt_in + ibase;
    uint32_t* poutI = pt_out + ibase;
    const int tid = threadIdx.x;
    const int tx = tid & 15, ty = tid >> 4;
    const int gx = x0 + 4 * tx;
    const int gy0 = y0 + 8 * ty;

    __shared__ float s2[16][68];

    uint4 cv[8];
    #pragma unroll
    for (int i = 0; i < 8; ++i)
        cv[i] = *(const uint4*)(pinI + (size_t)(gy0 + i) * WW + gx);
    uint4 upx = make_uint4(0u, 0u, 0u, 0u);
    if (gy0 > 0) upx = *(const uint4*)(pinI + (size_t)(gy0 - 1) * WW + gx);

    // left-neighbor packed values via lane shuffle (uniform execution)
    uint32_t lw[8];
    #pragma unroll
    for (int i = 0; i < 8; ++i) lw[i] = __shfl_up(cv[i].w, 1, 64);
    if (tx == 0) {
        #pragma unroll
        for (int i = 0; i < 8; ++i)
            lw[i] = (gx > 0) ? pinI[(size_t)(gy0 + i) * WW + gx - 1] : 0u;
    }

    float o[8][4];
    float accd = 0.f;
    #pragma unroll
    for (int i = 0; i < 8; ++i) {
        uint4 up = (i == 0) ? upx : cv[i - 1];
        uint2 hv = *(const uint2*)(hI + (size_t)(gy0 + i) * WW + gx);
        float2 ia = h2f(hv.x), ib = h2f(hv.y);
        float imv[4] = {ia.x, ia.y, ib.x, ib.y};
        uint32_t cc[4] = {cv[i].x, cv[i].y, cv[i].z, cv[i].w};
        uint32_t uu[4] = {up.x, up.y, up.z, up.w};
        uint32_t lt[4] = {lw[i], cv[i].x, cv[i].y, cv[i].z};
        #pragma unroll
        for (int j = 0; j < 4; ++j) {
            float2 cf = h2f(cc[j]);
            float dt = -(cf.x + cf.y) + h2f(uu[j]).x + h2f(lt[j]).y;
            o[i][j] = imv[j] + dt;
            accd += dt * dt;
        }
    }

    float rh[8];
    if (tx == 15 && x0 + 64 < WW) {
        uint32_t pc = (gy0 > 0) ? pinI[(size_t)(gy0 - 1) * WW + x0 + 64] : 0u;
        #pragma unroll
        for (int i = 0; i < 8; ++i) {
            size_t off = (size_t)(gy0 + i) * WW + x0 + 64;
            uint32_t c2 = pinI[off];
            float2 cf2 = h2f(c2);
            float dt2 = -(cf2.x + cf2.y) + h2f(pc).x + h2f(cv[i].w).y;
            rh[i] = __half2float(hI[off]) + dt2;
            pc = c2;
        }
    }

    float dh[4];
    if (ty == 15 && y0 + 128 < HH) {
        const int gyd = y0 + 128;
        size_t off = (size_t)gyd * WW + gx;
        uint4 dcv = *(const uint4*)(pinI + off);
        uint32_t dlw = __shfl_up(dcv.w, 1, 64);  // ty15 lanes all active together
        if (tx == 0) dlw = (gx > 0) ? pinI[off - 1] : 0u;
        uint2 dhh = *(const uint2*)(hI + off);
        float2 ia = h2f(dhh.x), ib = h2f(dhh.y);
        float imv[4] = {ia.x, ia.y, ib.x, ib.y};
        uint32_t dcc[4] = {dcv.x, dcv.y, dcv.z, dcv.w};
        uint32_t duu[4] = {cv[7].x, cv[7].y, cv[7].z, cv[7].w};
        uint32_t dlt[4] = {dlw, dcv.x, dcv.y, dcv.z};
        #pragma unroll
        for (int j = 0; j < 4; ++j) {
            float2 cf = h2f(dcc[j]);
            dh[j] = imv[j] + (-(cf.x + cf.y) + h2f(duu[j]).x + h2f(dlt[j]).y);
        }
    }

    *(float4*)&s2[ty][4 * tx] = make_float4(o[0][0], o[0][1], o[0][2], o[0][3]);
    __syncthreads();

    float accn = 0.f;
    #pragma unroll
    for (int i = 0; i < 8; ++i) {
        const int gy = gy0 + i;
        float rt = __shfl_down(o[i][0], 1, 64);
        if (tx == 15) rt = (x0 + 64 < WW) ? rh[i] : 0.f;
        float dnv[4];
        if (i < 7) {
            dnv[0] = o[i + 1][0]; dnv[1] = o[i + 1][1];
            dnv[2] = o[i + 1][2]; dnv[3] = o[i + 1][3];
        } else if (ty < 15) {
            float4 t = *(float4*)&s2[ty + 1][4 * tx];
            dnv[0] = t.x; dnv[1] = t.y; dnv[2] = t.z; dnv[3] = t.w;
        } else {
            dnv[0] = dh[0]; dnv[1] = dh[1]; dnv[2] = dh[2]; dnv[3] = dh[3];
        }
        uint32_t cc[4] = {cv[i].x, cv[i].y, cv[i].z, cv[i].w};
        uint32_t pv[4];
        #pragma unroll
        for (int j = 0; j < 4; ++j) {
            float ov = o[i][j];
            float g0 = (gy < HH - 1) ? dnv[j] - ov : 0.f;
            float rn = (j < 3) ? o[i][j + 1] : rt;
            float g1 = (gx + j < WW - 1) ? rn - ov : 0.f;
            float ss2 = g0 * g0 + g1 * g1;
            float nrm = (ss2 > 0.f) ? sqrtf(ss2) : 0.f;
            accn += nrm;
            float inv = 1.f / (1.f + tw * nrm);
            float2 cf = h2f(cc[j]);
            pv[j] = f2h2((cf.x - TAU * g0) * inv, (cf.y - TAU * g1) * inv);
        }
        *(uint4*)(poutI + (size_t)gy * WW + gx) = make_uint4(pv[0], pv[1], pv[2], pv[3]);
    }
    block_reduce_store(accd, accn,
                       &pd[it * NIMG * NBLK + im * NBLK + bid],
                       &pn[it * NIMG * NBLK + im * NBLK + bid], tid);
}

// Final: replay energy history once, pick snapshot ku, write out = imgh + div(pt[ku]).
__global__ __launch_bounds__(256, 3) void tv_final(
    const __half* __restrict__ imgh, const float* __restrict__ weight,
    const uint32_t* __restrict__ ptbase, float* __restrict__ out,
    const float* __restrict__ pd, const float* __restrict__ pn)
{
    const int im = blockIdx.z;
    const float w = weight[im / CCH];
    const int x0 = blockIdx.x * 64, y0 = blockIdx.y * 128;
    const size_t ibase = (size_t)im * HH * WW;
    const int tid = threadIdx.x;
    const int tx = tid & 15, ty = tid >> 4;
    const int gx = x0 + 4 * tx;
    const int gy0 = y0 + 8 * ty;

    __shared__ int sKf;
    if (tid < 64) {
        float n0 = (tid < NBLK) ? pn[im * NBLK + tid] : 0.f;
        for (int off = 32; off > 0; off >>= 1) n0 += __shfl_down(n0, off, 64);
        float E0 = w * __shfl(n0, 0, 64) / NUMEL;
        float Eprev = E0;
        int kf = -1;
        for (int k = 1; k <= 8; ++k) {
            float d = (tid < NBLK) ? pd[k * NIMG * NBLK + im * NBLK + tid] : 0.f;
            float n = (tid < NBLK) ? pn[k * NIMG * NBLK + im * NBLK + tid] : 0.f;
            for (int off = 32; off > 0; off >>= 1) {
                d += __shfl_down(d, off, 64);
                n += __shfl_down(n, off, 64);
            }
            float Ek = (__shfl(d, 0, 64) + w * __shfl(n, 0, 64)) / NUMEL;
            if (fabsf(Eprev - Ek) < TVEPS * E0) { kf = k; break; }
            Eprev = Ek;
        }
        if (tid == 0) sKf = kf;
    }
    __syncthreads();
    const int kf = sKf;
    const int ku = (kf >= 1) ? (kf - 1) : 8;

    const uint32_t* p = ptbase + (size_t)ku * PTELEMS + ibase;
    const __half* hI = imgh + ibase;
    float* outI = out + ibase;

    uint4 cv[8];
    #pragma unroll
    for (int i = 0; i < 8; ++i)
        cv[i] = *(const uint4*)(p + (size_t)(gy0 + i) * WW + gx);
    uint4 upx = make_uint4(0u, 0u, 0u, 0u);
    if (gy0 > 0) upx = *(const uint4*)(p + (size_t)(gy0 - 1) * WW + gx);
    uint32_t lw[8];
    #pragma unroll
    for (int i = 0; i < 8; ++i) lw[i] = __shfl_up(cv[i].w, 1, 64);
    if (tx == 0) {
        #pragma unroll
        for (int i = 0; i < 8; ++i)
            lw[i] = (gx > 0) ? p[(size_t)(gy0 + i) * WW + gx - 1] : 0u;
    }
    #pragma unroll
    for (int i = 0; i < 8; ++i) {
        uint4 up = (i == 0) ? upx : cv[i - 1];
        size_t off = (size_t)(gy0 + i) * WW + gx;
        uint2 hv = *(const uint2*)(hI + off);
        float2 ia = h2f(hv.x), ib = h2f(hv.y);
        float imv[4] = {ia.x, ia.y, ib.x, ib.y};
        uint32_t cc[4] = {cv[i].x, cv[i].y, cv[i].z, cv[i].w};
        uint32_t uu[4] = {up.x, up.y, up.z, up.w};
        uint32_t lt[4] = {lw[i], cv[i].x, cv[i].y, cv[i].z};
        float r[4];
        #pragma unroll
        for (int j = 0; j < 4; ++j) {
            float2 cf = h2f(cc[j]);
            r[j] = imv[j] + (-(cf.x + cf.y) + h2f(uu[j]).x + h2f(lt[j]).y);
        }
        *(float4*)(outI + off) = make_float4(r[0], r[1], r[2], r[3]);
    }
}

extern "C" void kernel_launch(void* const* d_in, const int* in_sizes, int n_in,
                              void* d_out, int out_size, void* d_ws, size_t ws_size,
                              hipStream_t stream)
{
    const float* img = (const float*)d_in[0];
    const float* weight = (const float*)d_in[1];
    float* out = (float*)d_out;
    float* pd = (float*)((char*)d_ws + 0);
    float* pn = (float*)((char*)d_ws + 32768);
    __half* imgh = (__half*)((char*)d_ws + 65536);
    uint32_t* ptbase = (uint32_t*)((char*)d_ws + 12648448);

    dim3 grid(8, 4, NIMG);
    dim3 block(256);

    tv_step0<<<grid, block, 0, stream>>>(img, weight, imgh, ptbase, pd, pn);
    for (int it = 1; it <= 8; ++it) {
        uint32_t* pin  = ptbase + (size_t)(it - 1) * PTELEMS;
        uint32_t* pout = ptbase + (size_t)it * PTELEMS;
        tv_stepN<<<grid, block, 0, stream>>>(imgh, weight, pin, pout, pd, pn, it);
    }
    tv_final<<<grid, block, 0, stream>>>(imgh, weight, ptbase, out, pd, pn);
}